// Round 18
// baseline (1997.414 us; speedup 1.0000x reference)
//
#include <hip/hip_runtime.h>

#define TB  512
#define TT  2048
#define HID 32

typedef _Float16 f16;
typedef float f32x2 __attribute__((ext_vector_type(2)));

// Numeric scheme (r5-r17, proven): fp64 h-state + update + pool sum; fp32
// dots/gates with hw exp2/rcp; fp16 h0 buffer. w = 1-z = sigma(-v);
// h' = h + w*(n-h). Broadcast value computed on the fp32 fast path (r17).
//
// r18: consumer FIFO reads hoisted out of the serial chain -- all 8 steps'
// fx/fn are read into registers right after the barrier (latency paid once
// per 8 steps, overlapped with the first CORE's dots), instead of one
// ~120-cyc ds_read sitting on EVERY step's chain. Values bit-identical.

#define PKFMA(ACC, A, B) \
  asm("v_pk_fma_f32 %0, %1, %2, %0" : "+v"(ACC) : "v"(A), "v"(B))

#define TWO_LOG2E 2.88539008177792682f

__device__ __forceinline__ float half_swap(float x, int half){
#if __has_builtin(__builtin_amdgcn_permlane32_swap)
  typedef unsigned uv2 __attribute__((ext_vector_type(2)));
  uv2 r = __builtin_amdgcn_permlane32_swap(__float_as_uint(x), __float_as_uint(x),
                                           false, false);
  return __uint_as_float(half ? r.x : r.y);
#else
  (void)half;
  return __shfl_xor(x, 32, 64);
#endif
}

// ---------------- Layer 0: fused input-GEMM (K=6) + GRU scan (r17 form) ----------------
__global__ __launch_bounds__(64,1)
void gru_l0(const float* __restrict__ x,
            const float* __restrict__ Wih_f, const float* __restrict__ Whh_f,
            const float* __restrict__ bih_f, const float* __restrict__ bhh_f,
            const float* __restrict__ Wih_b, const float* __restrict__ Whh_b,
            const float* __restrict__ bih_b, const float* __restrict__ bhh_b,
            f16* __restrict__ h0)
{
  const int job  = blockIdx.x;
  const int b    = job >> 1;
  const int dir  = job & 1;
  const int lane = threadIdx.x;
  const int j    = lane & 31;
  const int half = lane >> 5;

  const float* Wih = dir ? Wih_b : Wih_f;
  const float* Whh = dir ? Whh_b : Whh_f;
  const float* bih = dir ? bih_b : bih_f;
  const float* bhh = dir ? bhh_b : bhh_f;

  const int mrow = half * 32 + j;   // r-row (half0) or z-row (half1)
  const int nrow = 64 + j;          // n-row

  f32x2 wh_m2[16], wh_n2[16];
  f32x2 wi_m2[3],  wi_n2[3];
  {
    const float4* wm4 = (const float4*)(Whh + mrow*32);
#pragma unroll
    for (int q=0;q<8;q++){ float4 v=wm4[q];
      wh_m2[2*q]   = f32x2{v.x, v.y};
      wh_m2[2*q+1] = f32x2{v.z, v.w}; }
    const float4* wn4 = (const float4*)(Whh + nrow*32);
#pragma unroll
    for (int q=0;q<8;q++){ float4 v=wn4[q];
      wh_n2[2*q]   = f32x2{v.x, v.y};
      wh_n2[2*q+1] = f32x2{v.z, v.w}; }
#pragma unroll
    for (int i=0;i<3;i++){
      wi_m2[i] = f32x2{Wih[mrow*6+2*i], Wih[mrow*6+2*i+1]};
      wi_n2[i] = f32x2{Wih[nrow*6+2*i], Wih[nrow*6+2*i+1]};
    }
  }
  const float b_m   = bih[mrow] + bhh[mrow];
  const float b_ihn = bih[nrow];
  const float b_hhn = bhh[nrow];

  __shared__ __align__(16) float hlds[32];

  double hj = 0.;
  float  hjf = 0.f;

  const long t0    = dir ? (TT-1) : 0;
  const long tstep = dir ? -1 : 1;
  const float* xrow = x + ((size_t)b*TT + t0)*6;
  const long  xinc = tstep*6;
  f16* hout = h0 + ((size_t)b*TT + t0)*64 + dir*32;
  const long hinc = tstep*64;

  f32x2 hp[16];
#pragma unroll
  for (int k=0;k<16;k++) hp[k]=f32x2{0.f,0.f};

#define L0_STEP(XV)                                                          \
  {                                                                          \
    f32x2 SX2 = f32x2{0.f,0.f}, SN2 = f32x2{0.f,0.f};                        \
    PKFMA(SX2, wi_m2[0], XV[0]); PKFMA(SN2, wi_n2[0], XV[0]);                \
    PKFMA(SX2, wi_m2[1], XV[1]); PKFMA(SN2, wi_n2[1], XV[1]);                \
    PKFMA(SX2, wi_m2[2], XV[2]); PKFMA(SN2, wi_n2[2], XV[2]);                \
    float sx  = SX2.x + SX2.y;                                               \
    float sxn = SN2.x + SN2.y;                                               \
    f32x2 A0=f32x2{0.f,0.f}, A1=f32x2{0.f,0.f};                              \
    f32x2 A2=f32x2{0.f,0.f}, A3=f32x2{0.f,0.f};                              \
    f32x2 C0=f32x2{0.f,0.f}, C1=f32x2{0.f,0.f};                              \
    f32x2 C2=f32x2{0.f,0.f}, C3=f32x2{0.f,0.f};                              \
    _Pragma("unroll")                                                        \
    for (int k=0;k<4;k++){                                                   \
      PKFMA(A0, wh_m2[4*k],   hp[4*k]);                                      \
      PKFMA(A1, wh_m2[4*k+1], hp[4*k+1]);                                    \
      PKFMA(A2, wh_m2[4*k+2], hp[4*k+2]);                                    \
      PKFMA(A3, wh_m2[4*k+3], hp[4*k+3]);                                    \
      PKFMA(C0, wh_n2[4*k],   hp[4*k]);                                      \
      PKFMA(C1, wh_n2[4*k+1], hp[4*k+1]);                                    \
      PKFMA(C2, wh_n2[4*k+2], hp[4*k+2]);                                    \
      PKFMA(C3, wh_n2[4*k+3], hp[4*k+3]);                                    \
    }                                                                        \
    f32x2 At = A0+A1+A2+A3;                                                  \
    f32x2 Ct = C0+C1+C2+C3;                                                  \
    float hm   = At.x + At.y;                                                \
    float sn_h = Ct.x + Ct.y;                                                \
    float vf   = hm + sx + b_m;                                              \
    float varg = half ? -vf : vf;                                            \
    float ef   = __builtin_amdgcn_exp2f(varg * -1.44269504088896341f);       \
    float gmf  = __builtin_amdgcn_rcpf(1.f + ef);                            \
    float wf   = half_swap(gmf, half);                                       \
    float c1 = (sxn + b_ihn) * TWO_LOG2E;                                    \
    float c2 = (sn_h + b_hhn) * TWO_LOG2E;                                   \
    float e2 = __builtin_amdgcn_exp2f(fmaf(gmf, c2, c1));                    \
    float nnf= 1.f - 2.f*__builtin_amdgcn_rcpf(1.f + e2);                    \
    float hnf = fmaf(wf, nnf - hjf, hjf);                                    \
    if (lane < 32){ hlds[j] = hnf; hout[j] = (f16)hnf; }                     \
    hout += hinc;                                                            \
    hj = fma((double)wf, (double)nnf - hj, hj);                              \
    hjf = (float)hj;                                                         \
    {                                                                        \
      const float4* h4 = (const float4*)hlds;                                \
      _Pragma("unroll")                                                      \
      for (int q=0;q<8;q++){ float4 v=h4[q];                                 \
        hp[2*q]   = f32x2{v.x, v.y};                                         \
        hp[2*q+1] = f32x2{v.z, v.w}; }                                       \
    }                                                                        \
  }

  f32x2 xa[3], xb[3];
  {
    const float2* p=(const float2*)xrow;
    xa[0]=f32x2{p[0].x,p[0].y}; xa[1]=f32x2{p[1].x,p[1].y}; xa[2]=f32x2{p[2].x,p[2].y};
    const float2* q=(const float2*)(xrow + xinc);
    xb[0]=f32x2{q[0].x,q[0].y}; xb[1]=f32x2{q[1].x,q[1].y}; xb[2]=f32x2{q[2].x,q[2].y};
  }
  const float* xld = xrow + 2*xinc;

#pragma unroll 1
  for (int it=0; it<TT; it+=2){
    L0_STEP(xa)
    if (it+2 < TT){
      const float2* p=(const float2*)xld;
      xa[0]=f32x2{p[0].x,p[0].y}; xa[1]=f32x2{p[1].x,p[1].y}; xa[2]=f32x2{p[2].x,p[2].y};
      xld += xinc;
    }
    L0_STEP(xb)
    if (it+3 < TT){
      const float2* p=(const float2*)xld;
      xb[0]=f32x2{p[0].x,p[0].y}; xb[1]=f32x2{p[1].x,p[1].y}; xb[2]=f32x2{p[2].x,p[2].y};
      xld += xinc;
    }
  }
#undef L0_STEP
}

// ---------------- Layer 1: 2-wave producer/consumer, barrier per 8 steps ----------------
__global__ __launch_bounds__(128,2)
void gru_l1(const f16* __restrict__ h0,
            const float* __restrict__ Wih_f, const float* __restrict__ Whh_f,
            const float* __restrict__ bih_f, const float* __restrict__ bhh_f,
            const float* __restrict__ Wih_b, const float* __restrict__ Whh_b,
            const float* __restrict__ bih_b, const float* __restrict__ bhh_b,
            float* __restrict__ pooled)
{
  const int job  = blockIdx.x;
  const int b    = job >> 1;
  const int dir  = job & 1;
  const int tid  = threadIdx.x;
  const int wid  = tid >> 6;
  const int lane = tid & 63;
  const int j    = lane & 31;
  const int half = lane >> 5;

  const float* Wih = dir ? Wih_b : Wih_f;
  const float* Whh = dir ? Whh_b : Whh_f;
  const float* bih = dir ? bih_b : bih_f;
  const float* bhh = dir ? bhh_b : bhh_f;

  const int mrow = half * 32 + j;
  const int nrow = 64 + j;

  __shared__ __align__(16) float hlds[32];
  __shared__ __align__(16) float ring[16*64];
  __shared__ __align__(16) float fx[16][64];
  __shared__ __align__(16) float fn[16][64];   // FULL cross-half input n-dot

  const f16* h0b = h0 + (size_t)b*TT*64;
#define ROWF(LT) (h0b + (size_t)(dir ? (TT-1-(LT)) : (LT))*64)

  // producer: [0..31]=wi_m (64), [32..47]=wi_n (own 32)
  // consumer: [0..15]=wh_m (32), [16..31]=wh_n (FULL 32)
  f32x2 wreg[48];
  float b_m=0.f, b_ihn=0.f, b_hhn=0.f;

  if (wid == 1){
    const float4* wm4 = (const float4*)(Wih + mrow*64);
#pragma unroll
    for (int q=0;q<16;q++){ float4 v=wm4[q];
      wreg[2*q]   = f32x2{v.x,v.y};
      wreg[2*q+1] = f32x2{v.z,v.w}; }
    const float4* wn4 = (const float4*)(Wih + nrow*64 + half*32);
#pragma unroll
    for (int q=0;q<8;q++){ float4 v=wn4[q];
      wreg[32+2*q]   = f32x2{v.x,v.y};
      wreg[32+2*q+1] = f32x2{v.z,v.w}; }
  } else {
    const float4* hm4 = (const float4*)(Whh + mrow*32);
#pragma unroll
    for (int q=0;q<8;q++){ float4 v=hm4[q];
      wreg[2*q]   = f32x2{v.x,v.y};
      wreg[2*q+1] = f32x2{v.z,v.w}; }
    const float4* hn4 = (const float4*)(Whh + nrow*32);
#pragma unroll
    for (int q=0;q<8;q++){ float4 v=hn4[q];
      wreg[16+2*q]   = f32x2{v.x,v.y};
      wreg[16+2*q+1] = f32x2{v.z,v.w}; }
    b_m   = bih[mrow] + bhh[mrow];
    b_ihn = bih[nrow];
    b_hhn = bhh[nrow];
    if (lane < 32) hlds[lane] = 0.f;
  }

#define PRODUCE(S)                                                           \
  {                                                                          \
    const int slot = (S)&15;                                                 \
    const float4* s4 = (const float4*)(ring + slot*64);                      \
    f32x2 M0=f32x2{0.f,0.f}, M1=f32x2{0.f,0.f};                              \
    f32x2 NA=f32x2{0.f,0.f}, NB=f32x2{0.f,0.f};                              \
    _Pragma("unroll")                                                        \
    for (int q=0;q<16;q++){ float4 v=s4[q];                                  \
      f32x2 lo = f32x2{v.x,v.y}, hi = f32x2{v.z,v.w};                        \
      PKFMA(M0, wreg[2*q],   lo);                                            \
      PKFMA(M1, wreg[2*q+1], hi);                                            \
      if (q<8){ PKFMA(NA, wreg[32+2*q],   lo);                               \
                PKFMA(NA, wreg[32+2*q+1], hi); }                             \
      else {    PKFMA(NB, wreg[32+2*(q-8)],   lo);                           \
                PKFMA(NB, wreg[32+2*(q-8)+1], hi); }                         \
    }                                                                        \
    float own = half ? (NB.x+NB.y) : (NA.x+NA.y);                            \
    float oth = half_swap(own, half);                                        \
    fx[slot][lane] = (M0.x+M0.y)+(M1.x+M1.y);                                \
    fn[slot][lane] = own + oth;                                              \
  }

#define CORE(SX, SN)                                                         \
  {                                                                          \
    f32x2 A0=f32x2{0.f,0.f}, A1=f32x2{0.f,0.f};                              \
    f32x2 A2=f32x2{0.f,0.f}, A3=f32x2{0.f,0.f};                              \
    f32x2 C0=f32x2{0.f,0.f}, C1=f32x2{0.f,0.f};                              \
    f32x2 C2=f32x2{0.f,0.f}, C3=f32x2{0.f,0.f};                              \
    {                                                                        \
      const float4* h4 = (const float4*)hlds;                                \
      _Pragma("unroll")                                                      \
      for (int q=0;q<4;q++){                                                 \
        float4 v0=h4[2*q], v1=h4[2*q+1];                                     \
        f32x2 l0 = f32x2{v0.x,v0.y}, h0_ = f32x2{v0.z,v0.w};                 \
        f32x2 l1 = f32x2{v1.x,v1.y}, h1_ = f32x2{v1.z,v1.w};                 \
        PKFMA(A0, wreg[4*q],      l0);                                       \
        PKFMA(A1, wreg[4*q+1],    h0_);                                      \
        PKFMA(A2, wreg[4*q+2],    l1);                                       \
        PKFMA(A3, wreg[4*q+3],    h1_);                                      \
        PKFMA(C0, wreg[16+4*q],   l0);                                       \
        PKFMA(C1, wreg[16+4*q+1], h0_);                                      \
        PKFMA(C2, wreg[16+4*q+2], l1);                                       \
        PKFMA(C3, wreg[16+4*q+3], h1_);                                      \
      }                                                                      \
    }                                                                        \
    f32x2 At = A0+A1+A2+A3;                                                  \
    f32x2 Ct = C0+C1+C2+C3;                                                  \
    float hm   = At.x + At.y;                                                \
    float sn_h = Ct.x + Ct.y;                                                \
    float vf   = hm + (SX) + b_m;                                            \
    float varg = half ? -vf : vf;                                            \
    float ef   = __builtin_amdgcn_exp2f(varg * -1.44269504088896341f);       \
    float gmf  = __builtin_amdgcn_rcpf(1.f + ef);                            \
    float wf   = half_swap(gmf, half);                                       \
    float c1 = ((SN) + b_ihn) * TWO_LOG2E;                                   \
    float c2 = (sn_h + b_hhn) * TWO_LOG2E;                                   \
    float e2 = __builtin_amdgcn_exp2f(fmaf(gmf, c2, c1));                    \
    float nnf= 1.f - 2.f*__builtin_amdgcn_rcpf(1.f + e2);                    \
    float hnf = fmaf(wf, nnf - hjf, hjf);                                    \
    if (lane < 32) hlds[j] = hnf;                                            \
    hj = fma((double)wf, (double)nnf - hj, hj);                              \
    hjf = (float)hj;                                                         \
    psum += hj;                                                              \
  }

  double hj = 0., psum = 0.;
  float  hjf = 0.f;
  float pr[8];

  if (wid == 1){
    float pr0[16];
#pragma unroll
    for (int k=0;k<16;k++){
      int lt = k; if (lt > TT-1) lt = TT-1;
      pr0[k] = (float)ROWF(lt)[lane];
    }
#pragma unroll
    for (int k=0;k<16;k++) ring[k*64 + lane] = pr0[k];
#pragma unroll
    for (int k=0;k<8;k++){
      int lt = 16+k; if (lt > TT-1) lt = TT-1;
      pr[k] = (float)ROWF(lt)[lane];
    }
    PRODUCE(0) PRODUCE(1) PRODUCE(2) PRODUCE(3)
    PRODUCE(4) PRODUCE(5) PRODUCE(6) PRODUCE(7)
  }

#pragma unroll 1
  for (int t=0; t<TT; t+=8){
    __syncthreads();
    if (wid == 0){
      // hoist all 8 steps' FIFO reads off the serial chain (latency paid
      // once per iteration, overlapped with the first CORE's dots)
      float sxa[8], sna[8];
#pragma unroll
      for (int k=0;k<8;k++){
        sxa[k] = fx[(t+k)&15][lane];
        sna[k] = fn[(t+k)&15][lane];
      }
      CORE(sxa[0], sna[0]) CORE(sxa[1], sna[1])
      CORE(sxa[2], sna[2]) CORE(sxa[3], sna[3])
      CORE(sxa[4], sna[4]) CORE(sxa[5], sna[5])
      CORE(sxa[6], sna[6]) CORE(sxa[7], sna[7])
    } else {
#pragma unroll
      for (int k=0;k<8;k++) ring[((t+16+k)&15)*64 + lane] = pr[k];
#pragma unroll
      for (int k=0;k<8;k++){
        int lt = t+24+k; if (lt > TT-1) lt = TT-1;
        pr[k] = (float)ROWF(lt)[lane];
      }
      if (t+8 <= TT-1){
        PRODUCE(t+8)
        PRODUCE(t+9) PRODUCE(t+10) PRODUCE(t+11)
        PRODUCE(t+12) PRODUCE(t+13) PRODUCE(t+14) PRODUCE(t+15)
      }
    }
  }
#undef PRODUCE
#undef CORE
#undef ROWF

  if (wid == 0 && lane < 32)
    pooled[(size_t)b*64 + dir*32 + j] = (float)psum;
}

// ---------------- FC head: mean -> fc1(relu) -> fc2 ----------------
__global__ void fc_ep(const float* __restrict__ pooled,
                      const float* __restrict__ fc1w, const float* __restrict__ fc1b,
                      const float* __restrict__ fc2w, const float* __restrict__ fc2b,
                      float* __restrict__ out)
{
  int b = blockIdx.x*blockDim.x + threadIdx.x;
  if (b >= TB) return;
  float v[64];
  const float4* p4 = (const float4*)(pooled + (size_t)b*64);
#pragma unroll
  for (int q=0;q<16;q++){ float4 t=p4[q];
    v[4*q]  =t.x*(1.f/TT); v[4*q+1]=t.y*(1.f/TT);
    v[4*q+2]=t.z*(1.f/TT); v[4*q+3]=t.w*(1.f/TT); }
  float acc = fc2b[0];
#pragma unroll
  for (int g=0; g<16; g++){
    float s = fc1b[g];
    const float4* w4 = (const float4*)(fc1w + g*64);
#pragma unroll
    for (int q=0;q<16;q++){ float4 w=w4[q];
      s=fmaf(w.x,v[4*q],s);   s=fmaf(w.y,v[4*q+1],s);
      s=fmaf(w.z,v[4*q+2],s); s=fmaf(w.w,v[4*q+3],s); }
    s = fmaxf(s, 0.f);
    acc = fmaf(fc2w[g], s, acc);
  }
  out[b] = acc;
}

extern "C" void kernel_launch(void* const* d_in, const int* in_sizes, int n_in,
                              void* d_out, int out_size, void* d_ws, size_t ws_size,
                              hipStream_t stream)
{
  (void)in_sizes; (void)n_in; (void)out_size;

  const float* x     = (const float*)d_in[0];
  const float* Wih0f = (const float*)d_in[1];
  const float* Whh0f = (const float*)d_in[2];
  const float* bih0f = (const float*)d_in[3];
  const float* bhh0f = (const float*)d_in[4];
  const float* Wih0b = (const float*)d_in[5];
  const float* Whh0b = (const float*)d_in[6];
  const float* bih0b = (const float*)d_in[7];
  const float* bhh0b = (const float*)d_in[8];
  const float* Wih1f = (const float*)d_in[9];
  const float* Whh1f = (const float*)d_in[10];
  const float* bih1f = (const float*)d_in[11];
  const float* bhh1f = (const float*)d_in[12];
  const float* Wih1b = (const float*)d_in[13];
  const float* Whh1b = (const float*)d_in[14];
  const float* bih1b = (const float*)d_in[15];
  const float* bhh1b = (const float*)d_in[16];
  const float* fc1w  = (const float*)d_in[17];
  const float* fc1b  = (const float*)d_in[18];
  const float* fc2w  = (const float*)d_in[19];
  const float* fc2b  = (const float*)d_in[20];

  const size_t POOLED_BYTES = (size_t)TB * 64 * sizeof(float);
  const size_t PER_B        = (size_t)TT * 64 * sizeof(f16);
  float* pooled = (float*)d_ws;
  f16*   h0     = (f16*)((char*)d_ws + POOLED_BYTES);

  size_t avail = (ws_size > POOLED_BYTES) ? (ws_size - POOLED_BYTES) : 0;
  int Bc = (int)(avail / PER_B);
  if (Bc < 1)  Bc = 1;
  if (Bc > TB) Bc = TB;
  int nch = (TB + Bc - 1) / Bc;
  int Bce = (TB + nch - 1) / nch;

  for (int b0 = 0; b0 < TB; b0 += Bce) {
    int bc = (TB - b0 < Bce) ? (TB - b0) : Bce;
    hipLaunchKernelGGL(gru_l0, dim3(2*bc), dim3(64), 0, stream,
                       x + (size_t)b0*TT*6,
                       Wih0f,Whh0f,bih0f,bhh0f, Wih0b,Whh0b,bih0b,bhh0b, h0);
    hipLaunchKernelGGL(gru_l1, dim3(2*bc), dim3(128), 0, stream,
                       h0,
                       Wih1f,Whh1f,bih1f,bhh1f, Wih1b,Whh1b,bih1b,bhh1b,
                       pooled + (size_t)b0*64);
  }
  hipLaunchKernelGGL(fc_ep, dim3(2), dim3(256), 0, stream,
                     pooled, fc1w, fc1b, fc2w, fc2b, (float*)d_out);
}

// Round 19
// 1756.568 us; speedup vs baseline: 1.1371x; 1.1371x over previous
//
#include <hip/hip_runtime.h>

#define TB  512
#define TT  2048
#define HID 32

typedef _Float16 f16;
typedef float f32x2 __attribute__((ext_vector_type(2)));

// Numeric scheme (r5-r18, proven): fp64 h-state + update + pool sum; fp32
// dots/gates with hw exp2/rcp; fp16 h0 buffer. w = 1-z = sigma(-v);
// h' = h + w*(n-h). Broadcast value on the fp32 fast path (r17).
//
// r19: producer PRODUCE reads HALVED (8 b128 instead of 16) -- each half-wave
// reads only its 32-element half of the ring row and computes r/z/n PARTIALS;
// full dots assembled with 3 off-chain permlane swaps. Rationale: l1's
// consumer chain is identical to l0's yet costs +500 cyc/step; the one
// shared resource that differs is the per-CU LDS pipe (~120 LDS ops/CU-step
// vs l0's ~36) -- the consumer's chain-critical ds_write->ds_read queues
// behind the producer's ring-read flood.

#define PKFMA(ACC, A, B) \
  asm("v_pk_fma_f32 %0, %1, %2, %0" : "+v"(ACC) : "v"(A), "v"(B))

#define TWO_LOG2E 2.88539008177792682f

__device__ __forceinline__ float half_swap(float x, int half){
#if __has_builtin(__builtin_amdgcn_permlane32_swap)
  typedef unsigned uv2 __attribute__((ext_vector_type(2)));
  uv2 r = __builtin_amdgcn_permlane32_swap(__float_as_uint(x), __float_as_uint(x),
                                           false, false);
  return __uint_as_float(half ? r.x : r.y);
#else
  (void)half;
  return __shfl_xor(x, 32, 64);
#endif
}

// ---------------- Layer 0: fused input-GEMM (K=6) + GRU scan (r17 form) ----------------
__global__ __launch_bounds__(64,1)
void gru_l0(const float* __restrict__ x,
            const float* __restrict__ Wih_f, const float* __restrict__ Whh_f,
            const float* __restrict__ bih_f, const float* __restrict__ bhh_f,
            const float* __restrict__ Wih_b, const float* __restrict__ Whh_b,
            const float* __restrict__ bih_b, const float* __restrict__ bhh_b,
            f16* __restrict__ h0)
{
  const int job  = blockIdx.x;
  const int b    = job >> 1;
  const int dir  = job & 1;
  const int lane = threadIdx.x;
  const int j    = lane & 31;
  const int half = lane >> 5;

  const float* Wih = dir ? Wih_b : Wih_f;
  const float* Whh = dir ? Whh_b : Whh_f;
  const float* bih = dir ? bih_b : bih_f;
  const float* bhh = dir ? bhh_b : bhh_f;

  const int mrow = half * 32 + j;   // r-row (half0) or z-row (half1)
  const int nrow = 64 + j;          // n-row

  f32x2 wh_m2[16], wh_n2[16];
  f32x2 wi_m2[3],  wi_n2[3];
  {
    const float4* wm4 = (const float4*)(Whh + mrow*32);
#pragma unroll
    for (int q=0;q<8;q++){ float4 v=wm4[q];
      wh_m2[2*q]   = f32x2{v.x, v.y};
      wh_m2[2*q+1] = f32x2{v.z, v.w}; }
    const float4* wn4 = (const float4*)(Whh + nrow*32);
#pragma unroll
    for (int q=0;q<8;q++){ float4 v=wn4[q];
      wh_n2[2*q]   = f32x2{v.x, v.y};
      wh_n2[2*q+1] = f32x2{v.z, v.w}; }
#pragma unroll
    for (int i=0;i<3;i++){
      wi_m2[i] = f32x2{Wih[mrow*6+2*i], Wih[mrow*6+2*i+1]};
      wi_n2[i] = f32x2{Wih[nrow*6+2*i], Wih[nrow*6+2*i+1]};
    }
  }
  const float b_m   = bih[mrow] + bhh[mrow];
  const float b_ihn = bih[nrow];
  const float b_hhn = bhh[nrow];

  __shared__ __align__(16) float hlds[32];

  double hj = 0.;
  float  hjf = 0.f;

  const long t0    = dir ? (TT-1) : 0;
  const long tstep = dir ? -1 : 1;
  const float* xrow = x + ((size_t)b*TT + t0)*6;
  const long  xinc = tstep*6;
  f16* hout = h0 + ((size_t)b*TT + t0)*64 + dir*32;
  const long hinc = tstep*64;

  f32x2 hp[16];
#pragma unroll
  for (int k=0;k<16;k++) hp[k]=f32x2{0.f,0.f};

#define L0_STEP(XV)                                                          \
  {                                                                          \
    f32x2 SX2 = f32x2{0.f,0.f}, SN2 = f32x2{0.f,0.f};                        \
    PKFMA(SX2, wi_m2[0], XV[0]); PKFMA(SN2, wi_n2[0], XV[0]);                \
    PKFMA(SX2, wi_m2[1], XV[1]); PKFMA(SN2, wi_n2[1], XV[1]);                \
    PKFMA(SX2, wi_m2[2], XV[2]); PKFMA(SN2, wi_n2[2], XV[2]);                \
    float sx  = SX2.x + SX2.y;                                               \
    float sxn = SN2.x + SN2.y;                                               \
    f32x2 A0=f32x2{0.f,0.f}, A1=f32x2{0.f,0.f};                              \
    f32x2 A2=f32x2{0.f,0.f}, A3=f32x2{0.f,0.f};                              \
    f32x2 C0=f32x2{0.f,0.f}, C1=f32x2{0.f,0.f};                              \
    f32x2 C2=f32x2{0.f,0.f}, C3=f32x2{0.f,0.f};                              \
    _Pragma("unroll")                                                        \
    for (int k=0;k<4;k++){                                                   \
      PKFMA(A0, wh_m2[4*k],   hp[4*k]);                                      \
      PKFMA(A1, wh_m2[4*k+1], hp[4*k+1]);                                    \
      PKFMA(A2, wh_m2[4*k+2], hp[4*k+2]);                                    \
      PKFMA(A3, wh_m2[4*k+3], hp[4*k+3]);                                    \
      PKFMA(C0, wh_n2[4*k],   hp[4*k]);                                      \
      PKFMA(C1, wh_n2[4*k+1], hp[4*k+1]);                                    \
      PKFMA(C2, wh_n2[4*k+2], hp[4*k+2]);                                    \
      PKFMA(C3, wh_n2[4*k+3], hp[4*k+3]);                                    \
    }                                                                        \
    f32x2 At = A0+A1+A2+A3;                                                  \
    f32x2 Ct = C0+C1+C2+C3;                                                  \
    float hm   = At.x + At.y;                                                \
    float sn_h = Ct.x + Ct.y;                                                \
    float vf   = hm + sx + b_m;                                              \
    float varg = half ? -vf : vf;                                            \
    float ef   = __builtin_amdgcn_exp2f(varg * -1.44269504088896341f);       \
    float gmf  = __builtin_amdgcn_rcpf(1.f + ef);                            \
    float wf   = half_swap(gmf, half);                                       \
    float c1 = (sxn + b_ihn) * TWO_LOG2E;                                    \
    float c2 = (sn_h + b_hhn) * TWO_LOG2E;                                   \
    float e2 = __builtin_amdgcn_exp2f(fmaf(gmf, c2, c1));                    \
    float nnf= 1.f - 2.f*__builtin_amdgcn_rcpf(1.f + e2);                    \
    float hnf = fmaf(wf, nnf - hjf, hjf);                                    \
    if (lane < 32){ hlds[j] = hnf; hout[j] = (f16)hnf; }                     \
    hout += hinc;                                                            \
    hj = fma((double)wf, (double)nnf - hj, hj);                              \
    hjf = (float)hj;                                                         \
    {                                                                        \
      const float4* h4 = (const float4*)hlds;                                \
      _Pragma("unroll")                                                      \
      for (int q=0;q<8;q++){ float4 v=h4[q];                                 \
        hp[2*q]   = f32x2{v.x, v.y};                                         \
        hp[2*q+1] = f32x2{v.z, v.w}; }                                       \
    }                                                                        \
  }

  f32x2 xa[3], xb[3];
  {
    const float2* p=(const float2*)xrow;
    xa[0]=f32x2{p[0].x,p[0].y}; xa[1]=f32x2{p[1].x,p[1].y}; xa[2]=f32x2{p[2].x,p[2].y};
    const float2* q=(const float2*)(xrow + xinc);
    xb[0]=f32x2{q[0].x,q[0].y}; xb[1]=f32x2{q[1].x,q[1].y}; xb[2]=f32x2{q[2].x,q[2].y};
  }
  const float* xld = xrow + 2*xinc;

#pragma unroll 1
  for (int it=0; it<TT; it+=2){
    L0_STEP(xa)
    if (it+2 < TT){
      const float2* p=(const float2*)xld;
      xa[0]=f32x2{p[0].x,p[0].y}; xa[1]=f32x2{p[1].x,p[1].y}; xa[2]=f32x2{p[2].x,p[2].y};
      xld += xinc;
    }
    L0_STEP(xb)
    if (it+3 < TT){
      const float2* p=(const float2*)xld;
      xb[0]=f32x2{p[0].x,p[0].y}; xb[1]=f32x2{p[1].x,p[1].y}; xb[2]=f32x2{p[2].x,p[2].y};
      xld += xinc;
    }
  }
#undef L0_STEP
}

// ---------------- Layer 1: 2-wave producer/consumer, barrier per 8 steps ----------------
// Producer: HALF-SPLIT input dots -- each half-wave reads its 32-element half
// of the ring row (8 b128) and computes r/z/n partials; full dots assembled
// with 3 off-chain permlane swaps. Consumer unchanged (r17/r18).
__global__ __launch_bounds__(128,2)
void gru_l1(const f16* __restrict__ h0,
            const float* __restrict__ Wih_f, const float* __restrict__ Whh_f,
            const float* __restrict__ bih_f, const float* __restrict__ bhh_f,
            const float* __restrict__ Wih_b, const float* __restrict__ Whh_b,
            const float* __restrict__ bih_b, const float* __restrict__ bhh_b,
            float* __restrict__ pooled)
{
  const int job  = blockIdx.x;
  const int b    = job >> 1;
  const int dir  = job & 1;
  const int tid  = threadIdx.x;
  const int wid  = tid >> 6;
  const int lane = tid & 63;
  const int j    = lane & 31;
  const int half = lane >> 5;

  const float* Wih = dir ? Wih_b : Wih_f;
  const float* Whh = dir ? Whh_b : Whh_f;
  const float* bih = dir ? bih_b : bih_f;
  const float* bhh = dir ? bhh_b : bhh_f;

  const int mrow = half * 32 + j;
  const int nrow = 64 + j;

  __shared__ __align__(16) float hlds[32];
  __shared__ __align__(16) float ring[16*64];
  __shared__ __align__(16) float fx[16][64];
  __shared__ __align__(16) float fn[16][64];   // FULL cross-half input n-dot

  const f16* h0b = h0 + (size_t)b*TT*64;
#define ROWF(LT) (h0b + (size_t)(dir ? (TT-1-(LT)) : (LT))*64)

  // producer: [0..15]=w_r[j][half*32..+32], [16..31]=w_z[j][...], [32..47]=w_n[j][...]
  // consumer: [0..15]=wh_m (32), [16..31]=wh_n (FULL 32)
  f32x2 wreg[48];
  float b_m=0.f, b_ihn=0.f, b_hhn=0.f;

  if (wid == 1){
    const float4* wr4 = (const float4*)(Wih + (size_t)j*64      + half*32);
    const float4* wz4 = (const float4*)(Wih + (size_t)(32+j)*64 + half*32);
    const float4* wn4 = (const float4*)(Wih + (size_t)(64+j)*64 + half*32);
#pragma unroll
    for (int q=0;q<8;q++){ float4 v=wr4[q];
      wreg[2*q]   = f32x2{v.x,v.y};
      wreg[2*q+1] = f32x2{v.z,v.w}; }
#pragma unroll
    for (int q=0;q<8;q++){ float4 v=wz4[q];
      wreg[16+2*q]   = f32x2{v.x,v.y};
      wreg[16+2*q+1] = f32x2{v.z,v.w}; }
#pragma unroll
    for (int q=0;q<8;q++){ float4 v=wn4[q];
      wreg[32+2*q]   = f32x2{v.x,v.y};
      wreg[32+2*q+1] = f32x2{v.z,v.w}; }
  } else {
    const float4* hm4 = (const float4*)(Whh + mrow*32);
#pragma unroll
    for (int q=0;q<8;q++){ float4 v=hm4[q];
      wreg[2*q]   = f32x2{v.x,v.y};
      wreg[2*q+1] = f32x2{v.z,v.w}; }
    const float4* hn4 = (const float4*)(Whh + nrow*32);
#pragma unroll
    for (int q=0;q<8;q++){ float4 v=hn4[q];
      wreg[16+2*q]   = f32x2{v.x,v.y};
      wreg[16+2*q+1] = f32x2{v.z,v.w}; }
    b_m   = bih[mrow] + bhh[mrow];
    b_ihn = bih[nrow];
    b_hhn = bhh[nrow];
    if (lane < 32) hlds[lane] = 0.f;
  }

#define PRODUCE(S)                                                           \
  {                                                                          \
    const int slot = (S)&15;                                                 \
    const float4* s4 = (const float4*)(ring + slot*64 + half*32);            \
    f32x2 R0=f32x2{0.f,0.f}, R1=f32x2{0.f,0.f};                              \
    f32x2 Z0=f32x2{0.f,0.f}, Z1=f32x2{0.f,0.f};                              \
    f32x2 N0=f32x2{0.f,0.f}, N1=f32x2{0.f,0.f};                              \
    _Pragma("unroll")                                                        \
    for (int q=0;q<8;q++){ float4 v=s4[q];                                   \
      f32x2 lo = f32x2{v.x,v.y}, hi = f32x2{v.z,v.w};                        \
      PKFMA(R0, wreg[2*q],      lo);                                         \
      PKFMA(R1, wreg[2*q+1],    hi);                                         \
      PKFMA(Z0, wreg[16+2*q],   lo);                                         \
      PKFMA(Z1, wreg[16+2*q+1], hi);                                         \
      PKFMA(N0, wreg[32+2*q],   lo);                                         \
      PKFMA(N1, wreg[32+2*q+1], hi);                                         \
    }                                                                        \
    f32x2 Rt = R0+R1; f32x2 Zt = Z0+Z1; f32x2 Nt = N0+N1;                    \
    float rP = Rt.x+Rt.y, zP = Zt.x+Zt.y, nP = Nt.x+Nt.y;                    \
    float rF = rP + half_swap(rP, half);                                     \
    float zF = zP + half_swap(zP, half);                                     \
    fx[slot][lane] = half ? zF : rF;                                         \
    fn[slot][lane] = nP + half_swap(nP, half);                               \
  }

#define CORE(SX, SN)                                                         \
  {                                                                          \
    f32x2 A0=f32x2{0.f,0.f}, A1=f32x2{0.f,0.f};                              \
    f32x2 A2=f32x2{0.f,0.f}, A3=f32x2{0.f,0.f};                              \
    f32x2 C0=f32x2{0.f,0.f}, C1=f32x2{0.f,0.f};                              \
    f32x2 C2=f32x2{0.f,0.f}, C3=f32x2{0.f,0.f};                              \
    {                                                                        \
      const float4* h4 = (const float4*)hlds;                                \
      _Pragma("unroll")                                                      \
      for (int q=0;q<4;q++){                                                 \
        float4 v0=h4[2*q], v1=h4[2*q+1];                                     \
        f32x2 l0 = f32x2{v0.x,v0.y}, h0_ = f32x2{v0.z,v0.w};                 \
        f32x2 l1 = f32x2{v1.x,v1.y}, h1_ = f32x2{v1.z,v1.w};                 \
        PKFMA(A0, wreg[4*q],      l0);                                       \
        PKFMA(A1, wreg[4*q+1],    h0_);                                      \
        PKFMA(A2, wreg[4*q+2],    l1);                                       \
        PKFMA(A3, wreg[4*q+3],    h1_);                                      \
        PKFMA(C0, wreg[16+4*q],   l0);                                       \
        PKFMA(C1, wreg[16+4*q+1], h0_);                                      \
        PKFMA(C2, wreg[16+4*q+2], l1);                                       \
        PKFMA(C3, wreg[16+4*q+3], h1_);                                      \
      }                                                                      \
    }                                                                        \
    f32x2 At = A0+A1+A2+A3;                                                  \
    f32x2 Ct = C0+C1+C2+C3;                                                  \
    float hm   = At.x + At.y;                                                \
    float sn_h = Ct.x + Ct.y;                                                \
    float vf   = hm + (SX) + b_m;                                            \
    float varg = half ? -vf : vf;                                            \
    float ef   = __builtin_amdgcn_exp2f(varg * -1.44269504088896341f);       \
    float gmf  = __builtin_amdgcn_rcpf(1.f + ef);                            \
    float wf   = half_swap(gmf, half);                                       \
    float c1 = ((SN) + b_ihn) * TWO_LOG2E;                                   \
    float c2 = (sn_h + b_hhn) * TWO_LOG2E;                                   \
    float e2 = __builtin_amdgcn_exp2f(fmaf(gmf, c2, c1));                    \
    float nnf= 1.f - 2.f*__builtin_amdgcn_rcpf(1.f + e2);                    \
    float hnf = fmaf(wf, nnf - hjf, hjf);                                    \
    if (lane < 32) hlds[j] = hnf;                                            \
    hj = fma((double)wf, (double)nnf - hj, hj);                              \
    hjf = (float)hj;                                                         \
    psum += hj;                                                              \
  }

  double hj = 0., psum = 0.;
  float  hjf = 0.f;
  float pr[8];

  if (wid == 1){
    float pr0[16];
#pragma unroll
    for (int k=0;k<16;k++){
      int lt = k; if (lt > TT-1) lt = TT-1;
      pr0[k] = (float)ROWF(lt)[lane];
    }
#pragma unroll
    for (int k=0;k<16;k++) ring[k*64 + lane] = pr0[k];
#pragma unroll
    for (int k=0;k<8;k++){
      int lt = 16+k; if (lt > TT-1) lt = TT-1;
      pr[k] = (float)ROWF(lt)[lane];
    }
    PRODUCE(0) PRODUCE(1) PRODUCE(2) PRODUCE(3)
    PRODUCE(4) PRODUCE(5) PRODUCE(6) PRODUCE(7)
  }

#pragma unroll 1
  for (int t=0; t<TT; t+=8){
    __syncthreads();
    if (wid == 0){
      float sxa[8], sna[8];
#pragma unroll
      for (int k=0;k<8;k++){
        sxa[k] = fx[(t+k)&15][lane];
        sna[k] = fn[(t+k)&15][lane];
      }
      CORE(sxa[0], sna[0]) CORE(sxa[1], sna[1])
      CORE(sxa[2], sna[2]) CORE(sxa[3], sna[3])
      CORE(sxa[4], sna[4]) CORE(sxa[5], sna[5])
      CORE(sxa[6], sna[6]) CORE(sxa[7], sna[7])
    } else {
#pragma unroll
      for (int k=0;k<8;k++) ring[((t+16+k)&15)*64 + lane] = pr[k];
#pragma unroll
      for (int k=0;k<8;k++){
        int lt = t+24+k; if (lt > TT-1) lt = TT-1;
        pr[k] = (float)ROWF(lt)[lane];
      }
      if (t+8 <= TT-1){
        PRODUCE(t+8)
        PRODUCE(t+9) PRODUCE(t+10) PRODUCE(t+11)
        PRODUCE(t+12) PRODUCE(t+13) PRODUCE(t+14) PRODUCE(t+15)
      }
    }
  }
#undef PRODUCE
#undef CORE
#undef ROWF

  if (wid == 0 && lane < 32)
    pooled[(size_t)b*64 + dir*32 + j] = (float)psum;
}

// ---------------- FC head: mean -> fc1(relu) -> fc2 ----------------
__global__ void fc_ep(const float* __restrict__ pooled,
                      const float* __restrict__ fc1w, const float* __restrict__ fc1b,
                      const float* __restrict__ fc2w, const float* __restrict__ fc2b,
                      float* __restrict__ out)
{
  int b = blockIdx.x*blockDim.x + threadIdx.x;
  if (b >= TB) return;
  float v[64];
  const float4* p4 = (const float4*)(pooled + (size_t)b*64);
#pragma unroll
  for (int q=0;q<16;q++){ float4 t=p4[q];
    v[4*q]  =t.x*(1.f/TT); v[4*q+1]=t.y*(1.f/TT);
    v[4*q+2]=t.z*(1.f/TT); v[4*q+3]=t.w*(1.f/TT); }
  float acc = fc2b[0];
#pragma unroll
  for (int g=0; g<16; g++){
    float s = fc1b[g];
    const float4* w4 = (const float4*)(fc1w + g*64);
#pragma unroll
    for (int q=0;q<16;q++){ float4 w=w4[q];
      s=fmaf(w.x,v[4*q],s);   s=fmaf(w.y,v[4*q+1],s);
      s=fmaf(w.z,v[4*q+2],s); s=fmaf(w.w,v[4*q+3],s); }
    s = fmaxf(s, 0.f);
    acc = fmaf(fc2w[g], s, acc);
  }
  out[b] = acc;
}

extern "C" void kernel_launch(void* const* d_in, const int* in_sizes, int n_in,
                              void* d_out, int out_size, void* d_ws, size_t ws_size,
                              hipStream_t stream)
{
  (void)in_sizes; (void)n_in; (void)out_size;

  const float* x     = (const float*)d_in[0];
  const float* Wih0f = (const float*)d_in[1];
  const float* Whh0f = (const float*)d_in[2];
  const float* bih0f = (const float*)d_in[3];
  const float* bhh0f = (const float*)d_in[4];
  const float* Wih0b = (const float*)d_in[5];
  const float* Whh0b = (const float*)d_in[6];
  const float* bih0b = (const float*)d_in[7];
  const float* bhh0b = (const float*)d_in[8];
  const float* Wih1f = (const float*)d_in[9];
  const float* Whh1f = (const float*)d_in[10];
  const float* bih1f = (const float*)d_in[11];
  const float* bhh1f = (const float*)d_in[12];
  const float* Wih1b = (const float*)d_in[13];
  const float* Whh1b = (const float*)d_in[14];
  const float* bih1b = (const float*)d_in[15];
  const float* bhh1b = (const float*)d_in[16];
  const float* fc1w  = (const float*)d_in[17];
  const float* fc1b  = (const float*)d_in[18];
  const float* fc2w  = (const float*)d_in[19];
  const float* fc2b  = (const float*)d_in[20];

  const size_t POOLED_BYTES = (size_t)TB * 64 * sizeof(float);
  const size_t PER_B        = (size_t)TT * 64 * sizeof(f16);
  float* pooled = (float*)d_ws;
  f16*   h0     = (f16*)((char*)d_ws + POOLED_BYTES);

  size_t avail = (ws_size > POOLED_BYTES) ? (ws_size - POOLED_BYTES) : 0;
  int Bc = (int)(avail / PER_B);
  if (Bc < 1)  Bc = 1;
  if (Bc > TB) Bc = TB;
  int nch = (TB + Bc - 1) / Bc;
  int Bce = (TB + nch - 1) / nch;

  for (int b0 = 0; b0 < TB; b0 += Bce) {
    int bc = (TB - b0 < Bce) ? (TB - b0) : Bce;
    hipLaunchKernelGGL(gru_l0, dim3(2*bc), dim3(64), 0, stream,
                       x + (size_t)b0*TT*6,
                       Wih0f,Whh0f,bih0f,bhh0f, Wih0b,Whh0b,bih0b,bhh0b, h0);
    hipLaunchKernelGGL(gru_l1, dim3(2*bc), dim3(128), 0, stream,
                       h0,
                       Wih1f,Whh1f,bih1f,bhh1f, Wih1b,Whh1b,bih1b,bhh1b,
                       pooled + (size_t)b0*64);
  }
  hipLaunchKernelGGL(fc_ep, dim3(2), dim3(256), 0, stream,
                     pooled, fc1w, fc1b, fc2w, fc2b, (float*)d_out);
}